// Round 5
// baseline (186.727 us; speedup 1.0000x reference)
//
#include <hip/hip_runtime.h>
#include <stdint.h>

#define B_  2
#define S_  2048
#define D_  1024
#define H_  16
#define HD_ 64
#define TOK (B_*S_)   // 4096

typedef __bf16 bf16x8 __attribute__((ext_vector_type(8)));
typedef __bf16 bf16x4 __attribute__((ext_vector_type(4)));
typedef float  f32x4  __attribute__((ext_vector_type(4)));

static_assert(sizeof(bf16x8) == 16, "bf16x8 must be 16B");
static_assert(sizeof(bf16x4) == 8,  "bf16x4 must be 8B");

__device__ __forceinline__ float fexp2(float x) { return __builtin_amdgcn_exp2f(x); }

__device__ __forceinline__ f32x4 mfma16(bf16x8 a, bf16x8 b, f32x4 c) {
    return __builtin_amdgcn_mfma_f32_16x16x32_bf16(a, b, c, 0, 0, 0);
}

// ---------------------------------------------------------------------------
// K0a: Wo [1024(in)][1024(out)] fp32 -> WoT [out][in] bf16. grid (16,16).
// ---------------------------------------------------------------------------
__global__ __launch_bounds__(256) void k_transpose_wo(
    const float* __restrict__ Wo, unsigned short* __restrict__ WoT)
{
    __shared__ float t[64][65];
    const int i0 = blockIdx.x * 64;
    const int o0 = blockIdx.y * 64;
    const int tid = threadIdx.x;
    #pragma unroll
    for (int p = 0; p < 16; ++p) {
        int idx = tid + p * 256;
        int r = idx >> 6, c = idx & 63;
        t[r][c] = Wo[(size_t)(i0 + r) * D_ + o0 + c];
    }
    __syncthreads();
    #pragma unroll
    for (int p = 0; p < 16; ++p) {
        int idx = tid + p * 256;
        int r = idx >> 6, c = idx & 63;
        reinterpret_cast<__bf16*>(WoT)[(size_t)(o0 + r) * D_ + i0 + c] = (__bf16)t[c][r];
    }
}

// ---------------------------------------------------------------------------
// K0b: Wq/Wk/Wv [H][d][e] fp32 -> WT [z][h][e][d] bf16. grid (H,3), block 256.
// ---------------------------------------------------------------------------
__global__ __launch_bounds__(256) void k_transpose_w(
    const float* __restrict__ Wq, const float* __restrict__ Wk,
    const float* __restrict__ Wv, unsigned short* __restrict__ WT)
{
    __shared__ float t[64][65];
    const int h = blockIdx.x, z = blockIdx.y;
    const float* W = (z == 0) ? Wq : (z == 1) ? Wk : Wv;
    const int tid = threadIdx.x;
    #pragma unroll
    for (int p = 0; p < 4; ++p) {
        int idx = tid + p * 256;
        int r = idx >> 4, c4 = (idx & 15) * 4;
        *reinterpret_cast<float4*>(&t[r][c4]) =
            *reinterpret_cast<const float4*>(&W[h * 4096 + r * 64 + c4]);
    }
    __syncthreads();
    // thread i: e = i>>2, d-block = (i&3)*16 (two bf16x8 writes)
    const int e = tid >> 2, db = (tid & 3) * 16;
    __bf16* out = reinterpret_cast<__bf16*>(WT) + ((size_t)(z * H_ + h) * 64 + e) * 64 + db;
    #pragma unroll
    for (int jj = 0; jj < 2; ++jj) {
        bf16x8 v;
        #pragma unroll
        for (int j = 0; j < 8; ++j) v[j] = (__bf16)t[db + jj * 8 + j][e];
        *reinterpret_cast<bf16x8*>(out + jj * 8) = v;
    }
}

// ---------------------------------------------------------------------------
// K1 (v3): QKV projection, fused z-loop (X staged ONCE), MFMA.
//  - X tile (128 tok x 64) fp32->bf16, XOR-swizzled LDS.
//  - WT bf16 staged directly (pre-transposed by k_transpose_w), swizzled.
//  - z=0/1 (Q,K): swapped operands -> D[row=e][col=tok], coalesced bf16x4
//    stores to [B,H,S,HD]. z=2 (V): D[row=tok][col=e], bf16x4 along S to
//    [B,H,HD,S]. Q scaled by log2(e)/8.
// grid (TOK/128, H), block 256.
// ---------------------------------------------------------------------------
__global__ __launch_bounds__(256) void k_qkv(
    const float* __restrict__ X, const unsigned short* __restrict__ WT,
    const float* __restrict__ bq, const float* __restrict__ bk,
    const float* __restrict__ bv,
    unsigned short* __restrict__ Qo, unsigned short* __restrict__ Ko,
    unsigned short* __restrict__ Vt)
{
    __shared__ unsigned short Xl[128 * 64];      // bf16, swizzled slots
    __shared__ unsigned short Wl[3][64 * 64];    // bf16 W^T [e][d], swizzled

    const int tid  = threadIdx.x;
    const int lane = tid & 63, w = tid >> 6;
    const int g = lane >> 4, q = lane & 15;
    const int tok0 = blockIdx.x * 128;
    const int h    = blockIdx.y;

    // ---- stage X: fp32 read, cvt bf16, swizzled write ----
    #pragma unroll
    for (int i = 0; i < 4; ++i) {
        int c = tid + 256 * i;
        int row = c >> 3, slot = c & 7;
        const float* src = &X[(size_t)(tok0 + row) * D_ + h * HD_ + slot * 8];
        float4 x0 = *reinterpret_cast<const float4*>(src);
        float4 x1 = *reinterpret_cast<const float4*>(src + 4);
        bf16x8 v = { (__bf16)x0.x, (__bf16)x0.y, (__bf16)x0.z, (__bf16)x0.w,
                     (__bf16)x1.x, (__bf16)x1.y, (__bf16)x1.z, (__bf16)x1.w };
        *reinterpret_cast<bf16x8*>(
            reinterpret_cast<char*>(Xl) + row * 128 + ((slot ^ (row & 7)) * 16)) = v;
    }
    // ---- stage W^T bf16 for all 3 projections, swizzled ----
    #pragma unroll
    for (int zz = 0; zz < 3; ++zz) {
        #pragma unroll
        for (int i = 0; i < 2; ++i) {
            int c = tid + 256 * i;
            int e = c >> 3, slot = c & 7;
            bf16x8 v = *reinterpret_cast<const bf16x8*>(
                &WT[((size_t)(zz * H_ + h) * 64 + e) * 64 + slot * 8]);
            *reinterpret_cast<bf16x8*>(
                reinterpret_cast<char*>(Wl[zz]) + e * 128 + ((slot ^ (e & 7)) * 16)) = v;
        }
    }
    __syncthreads();

    const float scq = 0.18033688011112042f;  // log2(e)/8
    const int b  = tok0 >> 11;
    const int sb = (tok0 & (S_ - 1)) + w * 32;

    #pragma unroll
    for (int z = 0; z < 3; ++z) {
        const float* bb = (z == 0) ? bq : (z == 1) ? bk : bv;
        f32x4 acc[2][4] = {};
        #pragma unroll
        for (int s = 0; s < 2; ++s) {
            bf16x8 af[2], bfr[4];
            #pragma unroll
            for (int am = 0; am < 2; ++am) {
                int row  = w * 32 + am * 16 + q;
                int slot = (s * 4 + g) ^ (row & 7);
                af[am] = *reinterpret_cast<const bf16x8*>(
                    reinterpret_cast<const char*>(Xl) + row * 128 + slot * 16);
            }
            #pragma unroll
            for (int bn = 0; bn < 4; ++bn) {
                int row  = bn * 16 + q;
                int slot = (s * 4 + g) ^ (row & 7);
                bfr[bn] = *reinterpret_cast<const bf16x8*>(
                    reinterpret_cast<const char*>(Wl[z]) + row * 128 + slot * 16);
            }
            if (z == 2) {
                #pragma unroll
                for (int am = 0; am < 2; ++am)
                    #pragma unroll
                    for (int bn = 0; bn < 4; ++bn)
                        acc[am][bn] = mfma16(af[am], bfr[bn], acc[am][bn]);
            } else {
                #pragma unroll
                for (int am = 0; am < 2; ++am)
                    #pragma unroll
                    for (int bn = 0; bn < 4; ++bn)
                        acc[am][bn] = mfma16(bfr[bn], af[am], acc[am][bn]);
            }
        }
        // ---- epilogue ----
        if (z == 2) {
            // D[row=tok][col=e]: bf16x4 along S into Vt [B,H,HD,S]
            #pragma unroll
            for (int bn = 0; bn < 4; ++bn) {
                int e = bn * 16 + q;
                float bia = bb[h * HD_ + e];
                #pragma unroll
                for (int am = 0; am < 2; ++am) {
                    int s4 = sb + am * 16 + 4 * g;
                    bf16x4 ov = { (__bf16)(acc[am][bn][0] + bia), (__bf16)(acc[am][bn][1] + bia),
                                  (__bf16)(acc[am][bn][2] + bia), (__bf16)(acc[am][bn][3] + bia) };
                    *reinterpret_cast<bf16x4*>(
                        &Vt[((size_t)(b * H_ + h) * HD_ + e) * S_ + s4]) = ov;
                }
            }
        } else {
            // D[row=e][col=tok]: bf16x4 along HD into Q/K [B,H,S,HD]
            const float sc = (z == 0) ? scq : 1.0f;
            unsigned short* dst = (z == 0) ? Qo : Ko;
            #pragma unroll
            for (int bn = 0; bn < 4; ++bn) {
                float4 bia4 = *reinterpret_cast<const float4*>(&bb[h * HD_ + bn * 16 + 4 * g]);
                #pragma unroll
                for (int am = 0; am < 2; ++am) {
                    int tok = sb + am * 16 + q;
                    bf16x4 ov = { (__bf16)((acc[am][bn][0] + bia4.x) * sc),
                                  (__bf16)((acc[am][bn][1] + bia4.y) * sc),
                                  (__bf16)((acc[am][bn][2] + bia4.z) * sc),
                                  (__bf16)((acc[am][bn][3] + bia4.w) * sc) };
                    *reinterpret_cast<bf16x4*>(
                        &dst[((size_t)(b * H_ + h) * S_ + tok) * HD_ + bn * 16 + 4 * g]) = ov;
                }
            }
        }
    }
}

// ---------------------------------------------------------------------------
// K2 (v3): flash attention, 32 q-rows per wave (K/V frag reads amortized 2x).
// Swapped QK^T; dual (m,l) state; double-buffered K/V LDS; T14 async split;
// defer-max (T13). Block = 4 waves x 32 q = 128 q-rows; 32 keys/iter.
// grid (S/128, B*H), block 256.
// ---------------------------------------------------------------------------
__global__ __launch_bounds__(256) void k_attn(
    const unsigned short* __restrict__ Q,
    const unsigned short* __restrict__ K,
    const unsigned short* __restrict__ V,
    unsigned short* __restrict__ O)
{
    __shared__ unsigned short K_lds[2][32 * 72];  // 32 keys x (64 + 8 pad)
    __shared__ unsigned short V_lds[2][64 * 40];  // 64 dims x (32 + 8 pad)
    __shared__ unsigned short P_lds[4][32 * 40];  // per-wave: 32 q x (32 + 8 pad)

    const int bh = blockIdx.y;
    const unsigned short* Qp = Q + (size_t)bh * S_ * HD_;
    const unsigned short* Kp = K + (size_t)bh * S_ * HD_;
    const unsigned short* Vp = V + (size_t)bh * HD_ * S_;

    const int tid  = threadIdx.x;
    const int lane = tid & 63, w = tid >> 6;
    const int g = lane >> 4, q = lane & 15;
    const int q0   = blockIdx.x * 128 + w * 32;
    const int rowA = q0 + q, rowB = q0 + 16 + q;

    bf16x8 qfA0 = *reinterpret_cast<const bf16x8*>(&Qp[(size_t)rowA * HD_ + 8 * g]);
    bf16x8 qfA1 = *reinterpret_cast<const bf16x8*>(&Qp[(size_t)rowA * HD_ + 32 + 8 * g]);
    bf16x8 qfB0 = *reinterpret_cast<const bf16x8*>(&Qp[(size_t)rowB * HD_ + 8 * g]);
    bf16x8 qfB1 = *reinterpret_cast<const bf16x8*>(&Qp[(size_t)rowB * HD_ + 32 + 8 * g]);

    f32x4 accA[4] = {}, accB[4] = {};
    float mA = -3.0e38f, mB = -3.0e38f, lA = 0.0f, lB = 0.0f;

    const int kr = tid >> 3, ks = (tid & 7) * 8;
    const int vr = tid >> 2, vs = (tid & 3) * 8;
    unsigned short* Pw = P_lds[w];

    const unsigned short* kSrc = Kp + (size_t)kr * HD_ + ks;
    const unsigned short* vSrc = Vp + (size_t)vr * S_  + vs;

    {
        uint4 k0 = *reinterpret_cast<const uint4*>(kSrc);
        uint4 v0 = *reinterpret_cast<const uint4*>(vSrc);
        *reinterpret_cast<uint4*>(&K_lds[0][kr * 72 + ks]) = k0;
        *reinterpret_cast<uint4*>(&V_lds[0][vr * 40 + vs]) = v0;
    }
    __syncthreads();

    const int NT = S_ / 32;   // 64 tiles
    for (int t = 0; t < NT; ++t) {
        const int cur = t & 1, nxt = cur ^ 1;

        uint4 kn, vn;
        const bool more = (t + 1 < NT);
        if (more) {
            kn = *reinterpret_cast<const uint4*>(kSrc + (size_t)(t + 1) * 32 * HD_);
            vn = *reinterpret_cast<const uint4*>(vSrc + (size_t)(t + 1) * 32);
        }

        const unsigned short* Kb = K_lds[cur];
        const unsigned short* Vb = V_lds[cur];
        bf16x8 k00 = *reinterpret_cast<const bf16x8*>(&Kb[q * 72 + 8 * g]);
        bf16x8 k01 = *reinterpret_cast<const bf16x8*>(&Kb[q * 72 + 32 + 8 * g]);
        bf16x8 k10 = *reinterpret_cast<const bf16x8*>(&Kb[(16 + q) * 72 + 8 * g]);
        bf16x8 k11 = *reinterpret_cast<const bf16x8*>(&Kb[(16 + q) * 72 + 32 + 8 * g]);
        bf16x8 vf0 = *reinterpret_cast<const bf16x8*>(&Vb[(0 * 16 + q) * 40 + 8 * g]);
        bf16x8 vf1 = *reinterpret_cast<const bf16x8*>(&Vb[(1 * 16 + q) * 40 + 8 * g]);
        bf16x8 vf2 = *reinterpret_cast<const bf16x8*>(&Vb[(2 * 16 + q) * 40 + 8 * g]);
        bf16x8 vf3 = *reinterpret_cast<const bf16x8*>(&Vb[(3 * 16 + q) * 40 + 8 * g]);

        f32x4 z4 = {0.f, 0.f, 0.f, 0.f};
        f32x4 sA0 = mfma16(k00, qfA0, z4); sA0 = mfma16(k01, qfA1, sA0);
        f32x4 sA1 = mfma16(k10, qfA0, z4); sA1 = mfma16(k11, qfA1, sA1);
        f32x4 sB0 = mfma16(k00, qfB0, z4); sB0 = mfma16(k01, qfB1, sB0);
        f32x4 sB1 = mfma16(k10, qfB0, z4); sB1 = mfma16(k11, qfB1, sB1);

        float pmA = fmaxf(fmaxf(fmaxf(sA0[0], sA0[1]), fmaxf(sA0[2], sA0[3])),
                          fmaxf(fmaxf(sA1[0], sA1[1]), fmaxf(sA1[2], sA1[3])));
        float pmB = fmaxf(fmaxf(fmaxf(sB0[0], sB0[1]), fmaxf(sB0[2], sB0[3])),
                          fmaxf(fmaxf(sB1[0], sB1[1]), fmaxf(sB1[2], sB1[3])));
        if (!__all((pmA - mA <= 8.0f) && (pmB - mB <= 8.0f))) {
            float rA = pmA;
            rA = fmaxf(rA, __shfl_xor(rA, 16));
            rA = fmaxf(rA, __shfl_xor(rA, 32));
            float mnA = fmaxf(mA, rA);
            float sclA = fexp2(mA - mnA);
            mA = mnA; lA *= sclA;
            accA[0] *= sclA; accA[1] *= sclA; accA[2] *= sclA; accA[3] *= sclA;
            float rB = pmB;
            rB = fmaxf(rB, __shfl_xor(rB, 16));
            rB = fmaxf(rB, __shfl_xor(rB, 32));
            float mnB = fmaxf(mB, rB);
            float sclB = fexp2(mB - mnB);
            mB = mnB; lB *= sclB;
            accB[0] *= sclB; accB[1] *= sclB; accB[2] *= sclB; accB[3] *= sclB;
        }
        float pA0 = fexp2(sA0[0] - mA), pA1 = fexp2(sA0[1] - mA);
        float pA2 = fexp2(sA0[2] - mA), pA3 = fexp2(sA0[3] - mA);
        float pA4 = fexp2(sA1[0] - mA), pA5 = fexp2(sA1[1] - mA);
        float pA6 = fexp2(sA1[2] - mA), pA7 = fexp2(sA1[3] - mA);
        float pB0 = fexp2(sB0[0] - mB), pB1 = fexp2(sB0[1] - mB);
        float pB2 = fexp2(sB0[2] - mB), pB3 = fexp2(sB0[3] - mB);
        float pB4 = fexp2(sB1[0] - mB), pB5 = fexp2(sB1[1] - mB);
        float pB6 = fexp2(sB1[2] - mB), pB7 = fexp2(sB1[3] - mB);
        lA += ((pA0 + pA1) + (pA2 + pA3)) + ((pA4 + pA5) + (pA6 + pA7));
        lB += ((pB0 + pB1) + (pB2 + pB3)) + ((pB4 + pB5) + (pB6 + pB7));

        bf16x4 a0 = { (__bf16)pA0, (__bf16)pA1, (__bf16)pA2, (__bf16)pA3 };
        bf16x4 a1 = { (__bf16)pA4, (__bf16)pA5, (__bf16)pA6, (__bf16)pA7 };
        bf16x4 b0 = { (__bf16)pB0, (__bf16)pB1, (__bf16)pB2, (__bf16)pB3 };
        bf16x4 b1 = { (__bf16)pB4, (__bf16)pB5, (__bf16)pB6, (__bf16)pB7 };
        *reinterpret_cast<bf16x4*>(&Pw[q * 40 + 4 * g])             = a0;
        *reinterpret_cast<bf16x4*>(&Pw[q * 40 + 16 + 4 * g])        = a1;
        *reinterpret_cast<bf16x4*>(&Pw[(16 + q) * 40 + 4 * g])      = b0;
        *reinterpret_cast<bf16x4*>(&Pw[(16 + q) * 40 + 16 + 4 * g]) = b1;

        bf16x8 pfA = *reinterpret_cast<const bf16x8*>(&Pw[q * 40 + 8 * g]);
        bf16x8 pfB = *reinterpret_cast<const bf16x8*>(&Pw[(16 + q) * 40 + 8 * g]);
        accA[0] = mfma16(vf0, pfA, accA[0]);
        accA[1] = mfma16(vf1, pfA, accA[1]);
        accA[2] = mfma16(vf2, pfA, accA[2]);
        accA[3] = mfma16(vf3, pfA, accA[3]);
        accB[0] = mfma16(vf0, pfB, accB[0]);
        accB[1] = mfma16(vf1, pfB, accB[1]);
        accB[2] = mfma16(vf2, pfB, accB[2]);
        accB[3] = mfma16(vf3, pfB, accB[3]);

        if (more) {
            *reinterpret_cast<uint4*>(&K_lds[nxt][kr * 72 + ks]) = kn;
            *reinterpret_cast<uint4*>(&V_lds[nxt][vr * 40 + vs]) = vn;
        }
        __syncthreads();
    }

    // ---- epilogue ----
    lA += __shfl_xor(lA, 16);  lA += __shfl_xor(lA, 32);
    lB += __shfl_xor(lB, 16);  lB += __shfl_xor(lB, 32);
    const float invA = 1.0f / lA, invB = 1.0f / lB;
    const int b = bh >> 4, h = bh & 15;
    __bf16* Ob = reinterpret_cast<__bf16*>(O);
    size_t rA_ = (size_t)(b * S_ + rowA) * D_ + h * HD_ + 4 * g;
    size_t rB_ = (size_t)(b * S_ + rowB) * D_ + h * HD_ + 4 * g;
    #pragma unroll
    for (int d = 0; d < 4; ++d) {
        bf16x4 oa = { (__bf16)(accA[d][0]*invA), (__bf16)(accA[d][1]*invA),
                      (__bf16)(accA[d][2]*invA), (__bf16)(accA[d][3]*invA) };
        bf16x4 ob = { (__bf16)(accB[d][0]*invB), (__bf16)(accB[d][1]*invB),
                      (__bf16)(accB[d][2]*invB), (__bf16)(accB[d][3]*invB) };
        *reinterpret_cast<bf16x4*>(&Ob[rA_ + 16 * d]) = oa;
        *reinterpret_cast<bf16x4*>(&Ob[rB_ + 16 * d]) = ob;
    }
}

// ---------------------------------------------------------------------------
// K3: out = O_attn(bf16) @ WoT + bo, fp32. 128x128 tile, BK=64, dbuf swizzled
// LDS, reg-staged async split. grid (TOK/128, D/128), block 256.
// ---------------------------------------------------------------------------
__global__ __launch_bounds__(256) void k_out(
    const unsigned short* __restrict__ A,
    const unsigned short* __restrict__ Wt,
    const float* __restrict__ bo,
    float* __restrict__ C)
{
    __shared__ unsigned short Al[2][128 * 64];
    __shared__ unsigned short Bl[2][128 * 64];

    const int tid  = threadIdx.x;
    const int lane = tid & 63, w = tid >> 6;
    const int g = lane >> 4, q = lane & 15;
    const int wr = w & 1, wc = w >> 1;
    const int m0 = blockIdx.x * 128;
    const int n0 = blockIdx.y * 128;

    int    sbyte[4];
    size_t sgA[4], sgB[4];
    #pragma unroll
    for (int i = 0; i < 4; ++i) {
        int c = tid + 256 * i;
        int row = c >> 3, slot = c & 7;
        sbyte[i] = row * 128 + ((slot ^ (row & 7)) * 16);
        sgA[i] = (size_t)(m0 + row) * D_ + slot * 8;
        sgB[i] = (size_t)(n0 + row) * D_ + slot * 8;
    }

    uint4 ra[4], rb[4];
    #pragma unroll
    for (int i = 0; i < 4; ++i) {
        ra[i] = *reinterpret_cast<const uint4*>(A  + sgA[i]);
        rb[i] = *reinterpret_cast<const uint4*>(Wt + sgB[i]);
    }
    #pragma unroll
    for (int i = 0; i < 4; ++i) {
        *reinterpret_cast<uint4*>(reinterpret_cast<char*>(Al[0]) + sbyte[i]) = ra[i];
        *reinterpret_cast<uint4*>(reinterpret_cast<char*>(Bl[0]) + sbyte[i]) = rb[i];
    }
    __syncthreads();

    f32x4 acc[4][4] = {};
    const int NKT = D_ / 64;
    for (int kt = 0; kt < NKT; ++kt) {
        const int cur = kt & 1, nxt = cur ^ 1;
        const bool more = (kt + 1 < NKT);
        if (more) {
            #pragma unroll
            for (int i = 0; i < 4; ++i) {
                ra[i] = *reinterpret_cast<const uint4*>(A  + sgA[i] + (kt + 1) * 64);
                rb[i] = *reinterpret_cast<const uint4*>(Wt + sgB[i] + (kt + 1) * 64);
            }
        }
        const char* Ab = reinterpret_cast<const char*>(Al[cur]);
        const char* Bb = reinterpret_cast<const char*>(Bl[cur]);
        #pragma unroll
        for (int s = 0; s < 2; ++s) {
            bf16x8 af[4], bfr[4];
            #pragma unroll
            for (int am = 0; am < 4; ++am) {
                int row  = wr * 64 + am * 16 + q;
                int slot = (s * 4 + g) ^ (row & 7);
                af[am] = *reinterpret_cast<const bf16x8*>(Ab + row * 128 + slot * 16);
            }
            #pragma unroll
            for (int bn = 0; bn < 4; ++bn) {
                int row  = wc * 64 + bn * 16 + q;
                int slot = (s * 4 + g) ^ (row & 7);
                bfr[bn] = *reinterpret_cast<const bf16x8*>(Bb + row * 128 + slot * 16);
            }
            #pragma unroll
            for (int am = 0; am < 4; ++am)
                #pragma unroll
                for (int bn = 0; bn < 4; ++bn)
                    acc[am][bn] = mfma16(af[am], bfr[bn], acc[am][bn]);
        }
        if (more) {
            #pragma unroll
            for (int i = 0; i < 4; ++i) {
                *reinterpret_cast<uint4*>(reinterpret_cast<char*>(Al[nxt]) + sbyte[i]) = ra[i];
                *reinterpret_cast<uint4*>(reinterpret_cast<char*>(Bl[nxt]) + sbyte[i]) = rb[i];
            }
        }
        __syncthreads();
    }

    #pragma unroll
    for (int bn = 0; bn < 4; ++bn) {
        int n = n0 + wc * 64 + bn * 16 + q;
        float bia = bo[n];
        #pragma unroll
        for (int am = 0; am < 4; ++am) {
            int mbase = m0 + wr * 64 + am * 16 + 4 * g;
            #pragma unroll
            for (int j = 0; j < 4; ++j)
                C[(size_t)(mbase + j) * D_ + n] = acc[am][bn][j] + bia;
        }
    }
}

// ---------------------------------------------------------------------------
extern "C" void kernel_launch(void* const* d_in, const int* in_sizes, int n_in,
                              void* d_out, int out_size, void* d_ws, size_t ws_size,
                              hipStream_t stream)
{
    const float* X  = (const float*)d_in[0];
    const float* Wq = (const float*)d_in[1];
    const float* bq = (const float*)d_in[2];
    const float* Wk = (const float*)d_in[3];
    const float* bk = (const float*)d_in[4];
    const float* Wv = (const float*)d_in[5];
    const float* bv = (const float*)d_in[6];
    const float* Wo = (const float*)d_in[7];
    const float* bo = (const float*)d_in[8];
    float* out = (float*)d_out;

    unsigned short* ws = (unsigned short*)d_ws;
    const size_t QN = (size_t)B_ * H_ * S_ * HD_;     // 4M elements
    unsigned short* Qb    = ws;                       // 8 MB
    unsigned short* Kb    = ws + QN;                  // 8 MB
    unsigned short* Vtb   = ws + 2 * QN;              // 8 MB
    unsigned short* Ob    = ws + 3 * QN;              // 8 MB
    unsigned short* WoT   = ws + 4 * QN;              // 2 MB
    unsigned short* WqkvT = ws + 4 * QN + (size_t)D_ * D_;  // 384 KB

    k_transpose_wo<<<dim3(16, 16), 256, 0, stream>>>(Wo, WoT);
    k_transpose_w<<<dim3(H_, 3), 256, 0, stream>>>(Wq, Wk, Wv, WqkvT);
    k_qkv<<<dim3(TOK / 128, H_), 256, 0, stream>>>(X, WqkvT, bq, bk, bv, Qb, Kb, Vtb);
    k_attn<<<dim3(S_ / 128, B_ * H_), 256, 0, stream>>>(Qb, Kb, Vtb, Ob);
    k_out<<<dim3(TOK / 128, D_ / 128), 256, 0, stream>>>(Ob, WoT, bo, out);
}